// Round 1
// 560.236 us; speedup vs baseline: 1.0013x; 1.0013x over previous
//
#include <hip/hip_runtime.h>

// ---------------------------------------------------------------------------
// GCN forward:  relu(x@W1+b1) -> gcnconv(Wc1) -> relu -> gcnconv(Wc2) -> relu
//               -> @W2 + b2
//
// R9: GEMM1 (inside k_fused1) double-buffered via register staging.
//     R8 analysis: fused1 = 150 us with VALUBusy 17%, HBM 11%, 0 bank
//     conflicts -> latency-bound (8 serial K-phases x ~900cy HBM latency,
//     ~3 blocks/CU). Fix: issue phase k+1 global loads before compute of
//     phase k, ds_write to alternate LDS buffer, ONE barrier per phase.
//     LDS 53 KB -> 3 blocks/CU (unchanged co-residency, latency now hidden
//     inside each block). Everything else identical to R8.
// ---------------------------------------------------------------------------

__device__ __forceinline__ unsigned bf16_rne(float f) {
    unsigned u = __float_as_uint(f);
    return (u + 0x7fffu + ((u >> 16) & 1u)) >> 16;   // finite inputs only
}

__device__ __forceinline__ void unpack8(uint4 p, float v[8]) {
    v[0] = __uint_as_float(p.x << 16); v[1] = __uint_as_float(p.x & 0xffff0000u);
    v[2] = __uint_as_float(p.y << 16); v[3] = __uint_as_float(p.y & 0xffff0000u);
    v[4] = __uint_as_float(p.z << 16); v[5] = __uint_as_float(p.z & 0xffff0000u);
    v[6] = __uint_as_float(p.w << 16); v[7] = __uint_as_float(p.w & 0xffff0000u);
}

// ============================= small build kernels =========================

__global__ __launch_bounds__(256) void k_zero_cnt(int* __restrict__ cnt, int n) {
    int i = blockIdx.x * 256 + threadIdx.x;
    if (i < n) cnt[i] = 0;
}

__global__ __launch_bounds__(256) void k_scan1(const int* __restrict__ cnt,
                                               int* __restrict__ ptr,
                                               int* __restrict__ bsum, int n) {
    __shared__ int s[256];
    const int t = threadIdx.x;
    const int i = blockIdx.x * 256 + t;
    int v = (i < n) ? cnt[i] : 0;
    s[t] = v;
    __syncthreads();
#pragma unroll
    for (int off = 1; off < 256; off <<= 1) {
        int x = (t >= off) ? s[t - off] : 0;
        __syncthreads();
        s[t] += x;
        __syncthreads();
    }
    if (i < n) ptr[i] = s[t] - v;
    if (t == 255) bsum[blockIdx.x] = s[255];
}

// block b adds sum(bsum[0..b-1]) to its 256 ptr entries (bsum is L2-hot)
__global__ __launch_bounds__(256) void k_scan23(int* __restrict__ ptr,
                                                const int* __restrict__ bsum,
                                                int n, int etot) {
    __shared__ int s[256];
    const int t = threadIdx.x;
    const int b = blockIdx.x;
    int partial = 0;
    for (int j = t; j < b; j += 256) partial += bsum[j];
    s[t] = partial;
    __syncthreads();
#pragma unroll
    for (int off = 128; off > 0; off >>= 1) {
        if (t < off) s[t] += s[t + off];
        __syncthreads();
    }
    const int add = s[0];
    int i = b * 256 + t;
    if (i < n) ptr[i] += add;
    if (b == 0 && t == 0) ptr[n] = etot;
}

__global__ __launch_bounds__(256) void k_scatter(const int* __restrict__ row,
                                                 const int* __restrict__ col,
                                                 const float* __restrict__ ew,
                                                 const int* __restrict__ ptr,
                                                 const int* __restrict__ rank,
                                                 int2* __restrict__ recs, int ne) {
    int i = blockIdx.x * 256 + threadIdx.x;
    if (i < ne) {
        int c = col[i];
        int pos = ptr[c] + rank[i];
        recs[pos] = make_int2(row[i], __float_as_int(ew[i]));
    }
}

__global__ __launch_bounds__(256) void k_csr_deg(const int* __restrict__ ptr,
                                                 const int2* __restrict__ recs,
                                                 float* __restrict__ dinv, int n) {
    int i = blockIdx.x * 256 + threadIdx.x;
    if (i < n) {
        int s = ptr[i], e = ptr[i + 1];
        float d = 1.0f;  // self-loop
        for (int j = s; j < e; ++j) d += __int_as_float(recs[j].y);
        dinv[i] = rsqrtf(d);
    }
}

// ============================= fused hist + GEMM1 ==========================
// blocks [0, gemmBlocks): h = relu(x@W1+b1), 128x64 tile, 8x4 microtile,
//   double-buffered K-loop (reg-staged: issue next phase's global loads,
//   compute current from LDS, ds_write to alternate buffer, 1 barrier/phase).
// blocks [gemmBlocks, ...): rank[e] = atomicAdd(&cnt[col[e]], 1).
__global__ __launch_bounds__(256) void k_fused1(const float* __restrict__ x,
                                                const float* __restrict__ W,
                                                const float* __restrict__ bias,
                                                float* __restrict__ h, int n,
                                                const int* __restrict__ col,
                                                int* __restrict__ cnt,
                                                int* __restrict__ rank, int ne,
                                                int gemmBlocks) {
    if (blockIdx.x >= gemmBlocks) {
        int i = (blockIdx.x - gemmBlocks) * 256 + threadIdx.x;
        if (i < ne) rank[i] = atomicAdd(&cnt[col[i]], 1);
        return;
    }

    __shared__ float xs[2][128 * 36];   // 2 x 18.4 KB, stride 36 (bank-spread)
    __shared__ float ws[2][32 * 64];    // 2 x 8 KB
    const int tid = threadIdx.x;
    const int row0 = blockIdx.x * 128;
    const int tx = tid & 15;         // cols tx*4 .. +3
    const int ty = tid >> 4;         // rows j*16 + ty
    float acc[8][4] = {};

    // staging registers for one K-phase
    float4 xr0, xr1, xr2, xr3;
    float4 wr0, wr1;

    // per-thread staging coordinates (constant across phases)
    const int wkr0 = tid >> 4,         wcc0 = (tid & 15) * 4;
    const int wkr1 = (tid + 256) >> 4, wcc1 = (tid & 15) * 4;
    const int xr_r0 = tid >> 3,           xr_c0 = (tid & 7) * 4;
    const int xr_r1 = (tid + 256) >> 3,   xr_c1 = (tid & 7) * 4;
    const int xr_r2 = (tid + 512) >> 3,   xr_c2 = (tid & 7) * 4;
    const int xr_r3 = (tid + 768) >> 3,   xr_c3 = (tid & 7) * 4;

#define LOAD_PHASE(KB)                                                         \
    do {                                                                       \
        const int k0_ = (KB) * 32;                                             \
        wr0 = *(const float4*)(W + (size_t)(k0_ + wkr0) * 64 + wcc0);          \
        wr1 = *(const float4*)(W + (size_t)(k0_ + wkr1) * 64 + wcc1);          \
        int row_;                                                              \
        row_ = row0 + xr_r0;                                                   \
        xr0 = (row_ < n) ? *(const float4*)(x + (size_t)row_ * 256 + k0_ + xr_c0) \
                         : make_float4(0.f, 0.f, 0.f, 0.f);                    \
        row_ = row0 + xr_r1;                                                   \
        xr1 = (row_ < n) ? *(const float4*)(x + (size_t)row_ * 256 + k0_ + xr_c1) \
                         : make_float4(0.f, 0.f, 0.f, 0.f);                    \
        row_ = row0 + xr_r2;                                                   \
        xr2 = (row_ < n) ? *(const float4*)(x + (size_t)row_ * 256 + k0_ + xr_c2) \
                         : make_float4(0.f, 0.f, 0.f, 0.f);                    \
        row_ = row0 + xr_r3;                                                   \
        xr3 = (row_ < n) ? *(const float4*)(x + (size_t)row_ * 256 + k0_ + xr_c3) \
                         : make_float4(0.f, 0.f, 0.f, 0.f);                    \
    } while (0)

#define STORE_PHASE(B)                                                         \
    do {                                                                       \
        *(float4*)(&ws[B][wkr0 * 64 + wcc0]) = wr0;                            \
        *(float4*)(&ws[B][wkr1 * 64 + wcc1]) = wr1;                            \
        *(float4*)(&xs[B][xr_r0 * 36 + xr_c0]) = xr0;                          \
        *(float4*)(&xs[B][xr_r1 * 36 + xr_c1]) = xr1;                          \
        *(float4*)(&xs[B][xr_r2 * 36 + xr_c2]) = xr2;                          \
        *(float4*)(&xs[B][xr_r3 * 36 + xr_c3]) = xr3;                          \
    } while (0)

    LOAD_PHASE(0);
    STORE_PHASE(0);
    __syncthreads();

#pragma unroll 1
    for (int kb = 0; kb < 8; ++kb) {
        const int cur = kb & 1;
        if (kb < 7) LOAD_PHASE(kb + 1);   // global loads in flight over compute

        const float* xcur = xs[cur];
        const float* wcur = ws[cur];
#pragma unroll
        for (int kk = 0; kk < 32; kk += 4) {
            float a[8][4];
#pragma unroll
            for (int j = 0; j < 8; ++j) {
                float4 av = *(const float4*)(xcur + (j * 16 + ty) * 36 + kk);
                a[j][0] = av.x; a[j][1] = av.y; a[j][2] = av.z; a[j][3] = av.w;
            }
#pragma unroll
            for (int qq = 0; qq < 4; ++qq) {
                float4 b = *(const float4*)(wcur + (kk + qq) * 64 + tx * 4);
#pragma unroll
                for (int j = 0; j < 8; ++j) {
                    acc[j][0] = fmaf(a[j][qq], b.x, acc[j][0]);
                    acc[j][1] = fmaf(a[j][qq], b.y, acc[j][1]);
                    acc[j][2] = fmaf(a[j][qq], b.z, acc[j][2]);
                    acc[j][3] = fmaf(a[j][qq], b.w, acc[j][3]);
                }
            }
        }

        if (kb < 7) {
            STORE_PHASE(cur ^ 1);   // other buffer: no WAR vs this phase's reads
            __syncthreads();        // publish for next phase
        }
    }
#undef LOAD_PHASE
#undef STORE_PHASE

    float4 bb = *(const float4*)(bias + tx * 4);
#pragma unroll
    for (int j = 0; j < 8; ++j) {
        int row = row0 + j * 16 + ty;
        if (row < n) {
            float4 o;
            o.x = fmaxf(acc[j][0] + bb.x, 0.f);
            o.y = fmaxf(acc[j][1] + bb.y, 0.f);
            o.z = fmaxf(acc[j][2] + bb.z, 0.f);
            o.w = fmaxf(acc[j][3] + bb.w, 0.f);
            *(float4*)(h + (size_t)row * 64 + tx * 4) = o;
        }
    }
}

// ============================= Conv dense part =============================
// t'[r] = bf16( dinv[r] * (hin @ W)[r] )   -- bf16, 128 B per row
__global__ __launch_bounds__(256) void k_conv(const float* __restrict__ hin,
                                              const float* __restrict__ W,
                                              const float* __restrict__ dinv,
                                              unsigned* __restrict__ tb,
                                              int n) {
    __shared__ float xs[64 * 68];
    __shared__ float ws[64 * 64];
    const int tid = threadIdx.x;
    const int row0 = blockIdx.x * 64;
    const int tx = tid & 15, ty = tid >> 4;

    {
        const float4* src = (const float4*)W;
        float4* dst = (float4*)ws;
#pragma unroll
        for (int i = 0; i < 4; ++i) dst[tid + i * 256] = src[tid + i * 256];
    }
#pragma unroll
    for (int i = 0; i < 4; ++i) {
        int f = tid + i * 256;
        int r = f >> 4;
        int c = (f & 15) * 4;
        int row = row0 + r;
        float4 v = make_float4(0.f, 0.f, 0.f, 0.f);
        if (row < n) v = *(const float4*)(hin + (size_t)row * 64 + c);
        *(float4*)(xs + r * 68 + c) = v;
    }
    __syncthreads();

    float acc[4][4] = {};
#pragma unroll
    for (int kk = 0; kk < 64; kk += 4) {
        float4 a[4], b[4];
#pragma unroll
        for (int j = 0; j < 4; ++j)
            a[j] = *(const float4*)(xs + (ty * 4 + j) * 68 + kk);
#pragma unroll
        for (int qq = 0; qq < 4; ++qq)
            b[qq] = *(const float4*)(ws + (kk + qq) * 64 + tx * 4);
#pragma unroll
        for (int j = 0; j < 4; ++j) {
            float aj[4] = {a[j].x, a[j].y, a[j].z, a[j].w};
#pragma unroll
            for (int qq = 0; qq < 4; ++qq) {
                acc[j][0] = fmaf(aj[qq], b[qq].x, acc[j][0]);
                acc[j][1] = fmaf(aj[qq], b[qq].y, acc[j][1]);
                acc[j][2] = fmaf(aj[qq], b[qq].z, acc[j][2]);
                acc[j][3] = fmaf(aj[qq], b[qq].w, acc[j][3]);
            }
        }
    }
#pragma unroll
    for (int j = 0; j < 4; ++j) {
        int row = row0 + ty * 4 + j;
        if (row < n) {
            float dv = dinv[row];
            uint2 w;
            w.x = bf16_rne(dv * acc[j][0]) | (bf16_rne(dv * acc[j][1]) << 16);
            w.y = bf16_rne(dv * acc[j][2]) | (bf16_rne(dv * acc[j][3]) << 16);
            *(uint2*)(tb + (size_t)row * 32 + tx * 2) = w;
        }
    }
}

// ============================= CSR aggregation =============================
__global__ __launch_bounds__(256) void k_agg(const int* __restrict__ ptr,
                                             const int2* __restrict__ recs,
                                             const float* __restrict__ dinv,
                                             const float* __restrict__ bias,
                                             const uint4* __restrict__ t4,
                                             float4* __restrict__ agg4, int n) {
    const int lane = threadIdx.x & 63;
    const int c = blockIdx.x * 4 + (threadIdx.x >> 6);
    if (c >= n) return;
    const int grp = lane >> 3;
    const int f = lane & 7;

    float acc[8] = {};
    if (grp == 0) {
        float v[8];
        unpack8(t4[(size_t)c * 8 + f], v);
#pragma unroll
        for (int i = 0; i < 8; ++i) acc[i] = v[i];
    }

    const int eEnd = ptr[c + 1];
    int e = ptr[c] + grp;
    int2 rec = (e < eEnd) ? recs[e] : make_int2(0, 0);
    while (e < eEnd) {
        int2 cur = rec;
        e += 8;
        if (e < eEnd) rec = recs[e];
        uint4 p = t4[(size_t)cur.x * 8 + f];
        float w = __int_as_float(cur.y);
        float v[8];
        unpack8(p, v);
#pragma unroll
        for (int i = 0; i < 8; ++i) acc[i] = fmaf(w, v[i], acc[i]);
    }

#pragma unroll
    for (int off = 8; off < 64; off <<= 1) {
#pragma unroll
        for (int i = 0; i < 8; ++i) acc[i] += __shfl_xor(acc[i], off, 64);
    }

    if (grp == 0) {
        const float wc = dinv[c];
        float4 b0 = ((const float4*)bias)[f * 2];
        float4 b1 = ((const float4*)bias)[f * 2 + 1];
        float4 o0, o1;
        o0.x = fmaxf(fmaf(wc, acc[0], b0.x), 0.f);
        o0.y = fmaxf(fmaf(wc, acc[1], b0.y), 0.f);
        o0.z = fmaxf(fmaf(wc, acc[2], b0.z), 0.f);
        o0.w = fmaxf(fmaf(wc, acc[3], b0.w), 0.f);
        o1.x = fmaxf(fmaf(wc, acc[4], b1.x), 0.f);
        o1.y = fmaxf(fmaf(wc, acc[5], b1.y), 0.f);
        o1.z = fmaxf(fmaf(wc, acc[6], b1.z), 0.f);
        o1.w = fmaxf(fmaf(wc, acc[7], b1.w), 0.f);
        agg4[(size_t)c * 16 + f * 2] = o0;
        agg4[(size_t)c * 16 + f * 2 + 1] = o1;
    }
}

// ============================= Final GEMM ==================================
__global__ __launch_bounds__(256) void k_final(const float* __restrict__ hin,
                                               const float* __restrict__ W,
                                               const float* __restrict__ bias,
                                               float* __restrict__ out, int n) {
    __shared__ float xs[64 * 68];
    __shared__ float ws[64 * 40];
    const int tid = threadIdx.x;
    const int row0 = blockIdx.x * 64;

    for (int i = tid; i < 640; i += 256)
        ((float4*)ws)[i] = ((const float4*)W)[i];
#pragma unroll
    for (int i = 0; i < 4; ++i) {
        int f = tid + i * 256;
        int r = f >> 4;
        int c = (f & 15) * 4;
        int row = row0 + r;
        float4 v = make_float4(0.f, 0.f, 0.f, 0.f);
        if (row < n) v = *(const float4*)(hin + (size_t)row * 64 + c);
        *(float4*)(xs + r * 68 + c) = v;
    }
    __syncthreads();

    const int tx = tid & 15, ty = tid >> 4;
    if (tx < 10) {
        float acc[4][4] = {};
#pragma unroll
        for (int kk = 0; kk < 64; kk += 4) {
            float4 a[4], b[4];
#pragma unroll
            for (int j = 0; j < 4; ++j)
                a[j] = *(const float4*)(xs + (ty * 4 + j) * 68 + kk);
#pragma unroll
            for (int qq = 0; qq < 4; ++qq)
                b[qq] = *(const float4*)(ws + (kk + qq) * 40 + tx * 4);
#pragma unroll
            for (int j = 0; j < 4; ++j) {
                float aj[4] = {a[j].x, a[j].y, a[j].z, a[j].w};
#pragma unroll
                for (int qq = 0; qq < 4; ++qq) {
                    acc[j][0] = fmaf(aj[qq], b[qq].x, acc[j][0]);
                    acc[j][1] = fmaf(aj[qq], b[qq].y, acc[j][1]);
                    acc[j][2] = fmaf(aj[qq], b[qq].z, acc[j][2]);
                    acc[j][3] = fmaf(aj[qq], b[qq].w, acc[j][3]);
                }
            }
        }
        float4 bb = *(const float4*)(bias + tx * 4);
#pragma unroll
        for (int j = 0; j < 4; ++j) {
            int row = row0 + ty * 4 + j;
            if (row < n) {
                float4 o = make_float4(acc[j][0] + bb.x, acc[j][1] + bb.y,
                                       acc[j][2] + bb.z, acc[j][3] + bb.w);
                *(float4*)(out + (size_t)row * 40 + tx * 4) = o;
            }
        }
    }
}

extern "C" void kernel_launch(void* const* d_in, const int* in_sizes, int n_in,
                              void* d_out, int out_size, void* d_ws, size_t ws_size,
                              hipStream_t stream) {
    const float* x   = (const float*)d_in[0];
    const int*   ei  = (const int*)d_in[1];
    const float* ew  = (const float*)d_in[2];
    const float* W1  = (const float*)d_in[3];
    const float* b1  = (const float*)d_in[4];
    const float* Wc1 = (const float*)d_in[5];
    const float* bc1 = (const float*)d_in[6];
    const float* Wc2 = (const float*)d_in[7];
    const float* bc2 = (const float*)d_in[8];
    const float* W2  = (const float*)d_in[9];
    const float* b2  = (const float*)d_in[10];
    float* out = (float*)d_out;

    const int N = in_sizes[0] / 256;
    const int E = in_sizes[2];
    const int* row = ei;
    const int* col = ei + E;

    // workspace layout:
    // recs[E int2] | bufA[64N f] | bufB[64N f] | dinv[N f] | cnt[N i]
    //   | ptr[N+1 i] | bsum[512 i] | rank[E i]
    int2*  recs = (int2*)d_ws;
    float* bufA = (float*)(recs + E);
    float* bufB = bufA + (size_t)N * 64;
    float* dinv = bufB + (size_t)N * 64;
    int*   cnt  = (int*)(dinv + N);
    int*   ptr  = cnt + N;
    int*   bsum = ptr + N + 1;
    int*   rank = bsum + 512;
    unsigned* tb = (unsigned*)bufB;

    const int gN = (N + 255) / 256;       // 391
    const int gE = (E + 255) / 256;       // 6250
    const int gG = (N + 63) / 64;         // 1563
    const int gA = (N + 3) / 4;           // 25000
    const int gB = (N + 127) / 128;       // 782 gemm blocks

    // --- zero counters, then fused [gemm1 || hist] ---
    k_zero_cnt<<<gN, 256, 0, stream>>>(cnt, N);
    k_fused1<<<gB + gE, 256, 0, stream>>>(x, W1, b1, bufA, N,
                                          col, cnt, rank, E, gB);

    // --- finish CSR build ---
    k_scan1<<<gN, 256, 0, stream>>>(cnt, ptr, bsum, N);
    k_scan23<<<gN, 256, 0, stream>>>(ptr, bsum, N, E);
    k_scatter<<<gE, 256, 0, stream>>>(row, col, ew, ptr, rank, recs, E);
    k_csr_deg<<<gN, 256, 0, stream>>>(ptr, recs, dinv, N);

    // --- conv1 ---
    k_conv<<<gG, 256, 0, stream>>>(bufA, Wc1, dinv, tb, N);
    k_agg<<<gA, 256, 0, stream>>>(ptr, recs, dinv, bc1, (const uint4*)tb,
                                  (float4*)bufA, N);

    // --- conv2 ---
    k_conv<<<gG, 256, 0, stream>>>(bufA, Wc2, dinv, tb, N);
    k_agg<<<gA, 256, 0, stream>>>(ptr, recs, dinv, bc2, (const uint4*)tb,
                                  (float4*)bufA, N);

    // --- out = agg2 @ W2 + b2 ---
    k_final<<<gG, 256, 0, stream>>>(bufA, W2, b2, out, N);
}